// Round 22
// baseline (104.174 us; speedup 1.0000x reference)
//
#include <hip/hip_runtime.h>

#define NQ_ 30000
#define NC_ 16
#define C_  128
#define NS_ 8192
#define QB2 32
#define NBLK2 ((NQ_ + QB2 - 1)/QB2)   // 938, last block half

typedef __attribute__((ext_vector_type(4))) float  f32x4;
typedef __attribute__((ext_vector_type(8))) short  s16x8;

// workspace layout (float offsets)
#define WS_PART  0         // 16 cls * 32 subchunks * 128 = 65536
#define WS_PCNT  65536     // 512
#define WS_T     66048     // 2048  (protos @ Wp + b1)
#define WS_PACK  68096     // shorts: W2frag[16384] Wqfrag[16384] pnfrag[2048]

__device__ inline short f2bf(float x){           // round-to-nearest-even bf16
  unsigned u = __float_as_uint(x);
  u += 0x7fffu + ((u >> 16) & 1u);
  return (short)(u >> 16);
}

// ---- kernel A: proto partial sums (blocks 0..255, labels via LDS, 2 row-subchunks)
//      + W2/Wq pack (blocks 256..271) ----
__global__ __launch_bounds__(256) void protoA(const float* __restrict__ sf,
                                              const int* __restrict__ lbl,
                                              const float* __restrict__ W1,
                                              const float* __restrict__ W2,
                                              float* __restrict__ ws){
  const int b = blockIdx.x;
  const int t = threadIdx.x;
  if (b < 256){
    __shared__ int ll[512];
    const int cls = b >> 4;
    const int ch  = b & 15;
    const int r0  = ch * 512;
    *(int2*)&ll[t*2] = *(const int2*)&lbl[r0 + t*2];   // one coalesced round-trip
    __syncthreads();
    const int sub = t >> 7;          // 0..1 : rows [sub*256, sub*256+256)
    const int c   = t & 127;
    const int i0  = sub * 256;
    float s0 = 0.f, s1 = 0.f; int cnt = 0;
    #pragma unroll 4
    for (int i = 0; i < 256; i += 2){
      if (ll[i0+i]   == cls){ s0 += sf[(size_t)(r0+i0+i  )*C_ + c]; ++cnt; }
      if (ll[i0+i+1] == cls){ s1 += sf[(size_t)(r0+i0+i+1)*C_ + c]; ++cnt; }
    }
    ws[WS_PART + ((size_t)(cls*32 + ch*2 + sub))*C_ + c] = s0 + s1;
    if (c == 0) ws[WS_PCNT + cls*32 + ch*2 + sub] = (float)cnt;
  } else {
    // pack W2 (g<16384) / Wq (g>=16384) into MFMA fragment order
    short* packo = (short*)(ws + WS_PACK);
    const int g0 = (b - 256)*2048 + t*8;     // 16 blocks x 2048 = 32768 exact
    const int gg = g0 & 16383;
    const int ln = (gg >> 3) & 63, ks = (gg >> 9) & 3, wvv = gg >> 11;
    const int kb = ks*32 + ((ln >> 4) & 3)*8;
    const int col = wvv*16 + (ln & 15);
    const float* src = (g0 < 16384) ? W2 : W1;    // Wq = W1 rows [0,128)
    s16x8 v;
    #pragma unroll
    for (int i = 0; i < 8; ++i) v[i] = f2bf(src[(size_t)(kb + i)*C_ + col]);
    *(s16x8*)&packo[g0] = v;
  }
}

// ---- kernel B: per-class finalize + pn-pack + tmat (16 blocks x 512 thr, 4-way c-split) ----
__global__ __launch_bounds__(512) void protoB(const float* __restrict__ W1,
                                              const float* __restrict__ b1,
                                              float* __restrict__ ws){
  __shared__ float pr[C_];
  __shared__ float sacc[4][C_];
  __shared__ float rns;
  const int n = blockIdx.x;
  const int t = threadIdx.x;
  const int h = t & 127;
  const int part = t >> 7;         // 0..3
  if (t < 128){
    float s = 0.f, cnt = 0.f;
    #pragma unroll 8
    for (int ch = 0; ch < 32; ++ch) s   += ws[WS_PART + ((size_t)(n*32 + ch))*C_ + h];
    #pragma unroll 8
    for (int ch = 0; ch < 32; ++ch) cnt += ws[WS_PCNT + n*32 + ch];
    pr[h] = (cnt > 0.f) ? s / fmaxf(cnt, 1.f) : 0.f;
  }
  __syncthreads();
  if (t < 64){
    float q = pr[t]*pr[t] + pr[t+64]*pr[t+64];
    q += __shfl_xor(q, 1);  q += __shfl_xor(q, 2);  q += __shfl_xor(q, 4);
    q += __shfl_xor(q, 8);  q += __shfl_xor(q, 16); q += __shfl_xor(q, 32);
    if (t == 0) rns = 1.f / fmaxf(sqrtf(q), 1e-8f);
  }
  // tmat partial: part p sums c in [p*32, p*32+32)  (pr ready after first sync)
  {
    float a = 0.f;
    const int c0 = part * 32;
    #pragma unroll 8
    for (int c = c0; c < c0 + 32; ++c) a = fmaf(pr[c], W1[(size_t)(C_ + c)*C_ + h], a);
    sacc[part][h] = a;
  }
  __syncthreads();   // rns + sacc ready
  if (t < 128){
    // pn-pack: thread h handles k=h for class n
    short* packo = (short*)(ws + WS_PACK);
    const int gg = ((h >> 5)*64 + ((h >> 3) & 3)*16 + n)*8 + (h & 7);
    packo[32768 + gg] = f2bf(pr[h] * rns);
    ws[WS_T + n*C_ + h] = b1[h] + ((sacc[0][h] + sacc[1][h]) + (sacc[2][h] + sacc[3][h]));
  }
}

// ---- fused main: EXACT R15 (75.1 us) structure; only change = nontemporal
//      stores for sim/cos (keep L2 for read-shared pack/tmat data) ----
__global__ __launch_bounds__(256, 3) void fused_main(const float* __restrict__ qfeat,
                                                     const float* __restrict__ W1,
                                                     const float* __restrict__ b2,
                                                     const float* __restrict__ ws,
                                                     float* __restrict__ out){
  __shared__ __align__(16) char un[16896];   // qfs[32][132] f32 | hfrag[4q*2048] bf16
  __shared__ float qw[QB2][132];
  __shared__ float tl16[NC_][132];
  __shared__ float cosl[QB2][NC_];
  __shared__ float rqn[QB2];
  __shared__ float wcl[C_];

  float (*qfs)[132] = (float(*)[132])un;
  short* hfrag = (short*)un;

  const int t    = threadIdx.x;
  const int lane = t & 63;
  const int wv   = t >> 6;          // 0..3
  const int fr   = lane & 15;
  const int fg   = lane >> 4;
  const int qbase = blockIdx.x * QB2;
  float* out_cos = out + (size_t)NQ_ * NC_ * C_;
  const short* pack = (const short*)(ws + WS_PACK);

  // stage qf (32x128, row-clamped for tail block), t-matrix, Wc — all coalesced
  {
    const int q = t >> 3, c = (t & 7) * 16;
    int gr = qbase + q; if (gr > NQ_ - 1) gr = NQ_ - 1;
    const float* src = qfeat + (size_t)gr*C_ + c;
    *(f32x4*)&qfs[q][c]    = *(const f32x4*)(src);
    *(f32x4*)&qfs[q][c+4]  = *(const f32x4*)(src + 4);
    *(f32x4*)&qfs[q][c+8]  = *(const f32x4*)(src + 8);
    *(f32x4*)&qfs[q][c+12] = *(const f32x4*)(src + 12);
    const int r2 = t >> 4, c2 = (t & 15) * 8;
    *(f32x4*)&tl16[r2][c2]   = *(const f32x4*)(ws + WS_T + r2*C_ + c2);
    *(f32x4*)&tl16[r2][c2+4] = *(const f32x4*)(ws + WS_T + r2*C_ + c2 + 4);
    if (t < 32) *(f32x4*)&wcl[t*4] = *(const f32x4*)(W1 + 2*C_*C_ + t*4);
  }
  __syncthreads();

  // 1/max(||q||, eps) — 32 queries x 8 threads = 256 threads
  {
    const int q = t >> 3, c0 = (t & 7) * 16;
    float s = 0.f;
    #pragma unroll
    for (int m = 0; m < 16; ++m){ float v = qfs[q][c0+m]; s = fmaf(v, v, s); }
    s += __shfl_xor(s, 1); s += __shfl_xor(s, 2); s += __shfl_xor(s, 4);
    if ((t & 7) == 0) rqn[q] = 1.f / fmaxf(sqrtf(s), 1e-8f);
  }

  // A-fragments: group 0 = query fr, group 1 = query fr+16
  s16x8 qfrA[4], qfrB[4];
  #pragma unroll
  for (int ks = 0; ks < 4; ++ks){
    const int c0 = ks*32 + fg*8;
    f32x4 a = *(const f32x4*)&qfs[fr][c0];
    f32x4 b = *(const f32x4*)&qfs[fr][c0+4];
    s16x8 v;
    v[0]=f2bf(a[0]); v[1]=f2bf(a[1]); v[2]=f2bf(a[2]); v[3]=f2bf(a[3]);
    v[4]=f2bf(b[0]); v[5]=f2bf(b[1]); v[6]=f2bf(b[2]); v[7]=f2bf(b[3]);
    qfrA[ks] = v;
    f32x4 a2 = *(const f32x4*)&qfs[fr+16][c0];
    f32x4 b2x = *(const f32x4*)&qfs[fr+16][c0+4];
    s16x8 w;
    w[0]=f2bf(a2[0]); w[1]=f2bf(a2[1]); w[2]=f2bf(a2[2]); w[3]=f2bf(a2[3]);
    w[4]=f2bf(b2x[0]); w[5]=f2bf(b2x[1]); w[6]=f2bf(b2x[2]); w[7]=f2bf(b2x[3]);
    qfrB[ks] = w;
  }
  // B-fragments of W2 for this wave's two col-tiles
  s16x8 w2f[2][4];
  float b2v[2];
  #pragma unroll
  for (int j = 0; j < 2; ++j){
    const int tt = wv*2 + j;
    #pragma unroll
    for (int ks = 0; ks < 4; ++ks)
      w2f[j][ks] = *(const s16x8*)&pack[((tt*4 + ks)*64 + lane)*8];
    b2v[j] = b2[tt*16 + fr];
  }
  __syncthreads();   // rqn ready; all qfs reads done

  // qW = qf @ Wq for BOTH query groups : wave wv covers col-tiles wv*2, wv*2+1
  #pragma unroll
  for (int g = 0; g < 2; ++g){
    #pragma unroll
    for (int j = 0; j < 2; ++j){
      const int tt = wv*2 + j;
      f32x4 dq = {0.f,0.f,0.f,0.f};
      #pragma unroll
      for (int ks = 0; ks < 4; ++ks)
        dq = __builtin_amdgcn_mfma_f32_16x16x32_bf16(g ? qfrB[ks] : qfrA[ks],
               *(const s16x8*)&pack[16384 + ((tt*4 + ks)*64 + lane)*8], dq, 0,0,0);
      #pragma unroll
      for (int r = 0; r < 4; ++r) qw[g*16 + fg*4 + r][tt*16 + fr] = dq[r];
    }
  }
  // cos: wave 0 -> group 0 (q 0..15), wave 1 -> group 1 (q 16..31)
  if (wv < 2){
    f32x4 dc = {0.f,0.f,0.f,0.f};
    #pragma unroll
    for (int ks = 0; ks < 4; ++ks)
      dc = __builtin_amdgcn_mfma_f32_16x16x32_bf16(wv ? qfrB[ks] : qfrA[ks],
             *(const s16x8*)&pack[32768 + (ks*64 + lane)*8], dc, 0,0,0);
    #pragma unroll
    for (int r = 0; r < 4; ++r){
      const int q = wv*16 + fg*4 + r;
      const float cv = dc[r] * rqn[q];
      cosl[q][fr] = cv;
      if (qbase + q < NQ_)
        __builtin_nontemporal_store(cv, &out_cos[(size_t)(qbase + q)*NC_ + fr]);
    }
  }
  __syncthreads();   // qw, cosl ready; qfs dead -> hfrag live

  // phase-A constants: wave wv == k-step; lane -> (class fr, k-group fg)
  const int k0 = wv*32 + fg*8;
  const f32x4 t8a = *(const f32x4*)&tl16[fr][k0];
  const f32x4 t8b = *(const f32x4*)&tl16[fr][k0+4];
  const f32x4 w8a = *(const f32x4*)&wcl[k0];
  const f32x4 w8b = *(const f32x4*)&wcl[k0+4];

  #pragma unroll
  for (int chunk = 0; chunk < 8; ++chunk){
    const int q0 = chunk * 4;
    if (qbase + q0 >= NQ_) break;    // block-uniform tail cut (no barrier divergence)
    // phase A: H = relu(qW + t_n + cos*Wc) -> bf16 fragments
    #pragma unroll
    for (int qq = 0; qq < 4; ++qq){
      const int q = q0 + qq;
      f32x4 qa = *(const f32x4*)&qw[q][k0];     // broadcast within fg-group
      f32x4 qb = *(const f32x4*)&qw[q][k0+4];
      const float cv = cosl[q][fr];
      s16x8 hv;
      #pragma unroll
      for (int jj = 0; jj < 4; ++jj)
        hv[jj] = f2bf(fmaxf(fmaf(cv, w8a[jj], qa[jj] + t8a[jj]), 0.f));
      #pragma unroll
      for (int jj = 0; jj < 4; ++jj)
        hv[4+jj] = f2bf(fmaxf(fmaf(cv, w8b[jj], qb[jj] + t8b[jj]), 0.f));
      *(s16x8*)&hfrag[qq*2048 + wv*512 + lane*8] = hv;   // b128, conflict-free
    }
    __syncthreads();
    // phase B: sim = H @ W2 + b2 ; one ds_read set feeds both col-tiles
    #pragma unroll
    for (int qq = 0; qq < 4; ++qq){
      const short* hb = &hfrag[qq*2048 + lane*8];
      s16x8 a0 = *(const s16x8*)&hb[0];
      s16x8 a1 = *(const s16x8*)&hb[512];
      s16x8 a2 = *(const s16x8*)&hb[1024];
      s16x8 a3 = *(const s16x8*)&hb[1536];
      const size_t qout = (size_t)(qbase + q0 + qq) * (NC_*C_);
      #pragma unroll
      for (int j = 0; j < 2; ++j){
        f32x4 acc = {b2v[j], b2v[j], b2v[j], b2v[j]};
        acc = __builtin_amdgcn_mfma_f32_16x16x32_bf16(a0, w2f[j][0], acc, 0,0,0);
        acc = __builtin_amdgcn_mfma_f32_16x16x32_bf16(a1, w2f[j][1], acc, 0,0,0);
        acc = __builtin_amdgcn_mfma_f32_16x16x32_bf16(a2, w2f[j][2], acc, 0,0,0);
        acc = __builtin_amdgcn_mfma_f32_16x16x32_bf16(a3, w2f[j][3], acc, 0,0,0);
        const int ocol = (wv*2 + j)*16 + fr;
        #pragma unroll
        for (int r = 0; r < 4; ++r)
          __builtin_nontemporal_store(acc[r], &out[qout + (fg*4 + r)*C_ + ocol]);
      }
    }
    __syncthreads();
  }
}

extern "C" void kernel_launch(void* const* d_in, const int* in_sizes, int n_in,
                              void* d_out, int out_size, void* d_ws, size_t ws_size,
                              hipStream_t stream){
  const float* sf  = (const float*)d_in[0];
  const int*   lbl = (const int*)  d_in[1];
  const float* qf  = (const float*)d_in[2];
  const float* W1  = (const float*)d_in[3];
  const float* b1  = (const float*)d_in[4];
  const float* W2  = (const float*)d_in[5];
  const float* b2  = (const float*)d_in[6];
  float* ws  = (float*)d_ws;
  float* out = (float*)d_out;

  protoA<<<272, 256, 0, stream>>>(sf, lbl, W1, W2, ws);
  protoB<<<NC_, 512, 0, stream>>>(W1, b1, ws);
  fused_main<<<NBLK2, 256, 0, stream>>>(qf, W1, b2, ws, out);
}

// Round 23
// 75.949 us; speedup vs baseline: 1.3716x; 1.3716x over previous
//
#include <hip/hip_runtime.h>

#define NQ_ 30000
#define NC_ 16
#define C_  128
#define NS_ 8192
#define QB2 32
#define NBLK2 ((NQ_ + QB2 - 1)/QB2)   // 938, last block half

typedef __attribute__((ext_vector_type(4))) float  f32x4;
typedef __attribute__((ext_vector_type(8))) short  s16x8;

// workspace layout (float offsets)
#define WS_PART  0         // 16 cls * 32 subchunks * 128 = 65536
#define WS_PCNT  65536     // 512
#define WS_T     66048     // 2048  (protos @ Wp + b1)
#define WS_PACK  68096     // shorts: W2frag[16384] Wqfrag[16384] pnfrag[2048]

__device__ inline short f2bf(float x){           // round-to-nearest-even bf16
  unsigned u = __float_as_uint(x);
  u += 0x7fffu + ((u >> 16) & 1u);
  return (short)(u >> 16);
}

// ---- kernel A: proto partial sums (blocks 0..255, labels via LDS, 2 row-subchunks)
//      + W2/Wq pack (blocks 256..271) ----
__global__ __launch_bounds__(256) void protoA(const float* __restrict__ sf,
                                              const int* __restrict__ lbl,
                                              const float* __restrict__ W1,
                                              const float* __restrict__ W2,
                                              float* __restrict__ ws){
  const int b = blockIdx.x;
  const int t = threadIdx.x;
  if (b < 256){
    __shared__ int ll[512];
    const int cls = b >> 4;
    const int ch  = b & 15;
    const int r0  = ch * 512;
    *(int2*)&ll[t*2] = *(const int2*)&lbl[r0 + t*2];   // one coalesced round-trip
    __syncthreads();
    const int sub = t >> 7;          // 0..1 : rows [sub*256, sub*256+256)
    const int c   = t & 127;
    const int i0  = sub * 256;
    float s0 = 0.f, s1 = 0.f; int cnt = 0;
    #pragma unroll 4
    for (int i = 0; i < 256; i += 2){
      if (ll[i0+i]   == cls){ s0 += sf[(size_t)(r0+i0+i  )*C_ + c]; ++cnt; }
      if (ll[i0+i+1] == cls){ s1 += sf[(size_t)(r0+i0+i+1)*C_ + c]; ++cnt; }
    }
    ws[WS_PART + ((size_t)(cls*32 + ch*2 + sub))*C_ + c] = s0 + s1;
    if (c == 0) ws[WS_PCNT + cls*32 + ch*2 + sub] = (float)cnt;
  } else {
    // pack W2 (g<16384) / Wq (g>=16384) into MFMA fragment order
    short* packo = (short*)(ws + WS_PACK);
    const int g0 = (b - 256)*2048 + t*8;     // 16 blocks x 2048 = 32768 exact
    const int gg = g0 & 16383;
    const int ln = (gg >> 3) & 63, ks = (gg >> 9) & 3, wvv = gg >> 11;
    const int kb = ks*32 + ((ln >> 4) & 3)*8;
    const int col = wvv*16 + (ln & 15);
    const float* src = (g0 < 16384) ? W2 : W1;    // Wq = W1 rows [0,128)
    s16x8 v;
    #pragma unroll
    for (int i = 0; i < 8; ++i) v[i] = f2bf(src[(size_t)(kb + i)*C_ + col]);
    *(s16x8*)&packo[g0] = v;
  }
}

// ---- kernel B: per-class finalize + pn-pack + tmat (16 blocks x 512 thr, 4-way c-split) ----
__global__ __launch_bounds__(512) void protoB(const float* __restrict__ W1,
                                              const float* __restrict__ b1,
                                              float* __restrict__ ws){
  __shared__ float pr[C_];
  __shared__ float sacc[4][C_];
  __shared__ float rns;
  const int n = blockIdx.x;
  const int t = threadIdx.x;
  const int h = t & 127;
  const int part = t >> 7;         // 0..3
  if (t < 128){
    float s = 0.f, cnt = 0.f;
    #pragma unroll 8
    for (int ch = 0; ch < 32; ++ch) s   += ws[WS_PART + ((size_t)(n*32 + ch))*C_ + h];
    #pragma unroll 8
    for (int ch = 0; ch < 32; ++ch) cnt += ws[WS_PCNT + n*32 + ch];
    pr[h] = (cnt > 0.f) ? s / fmaxf(cnt, 1.f) : 0.f;
  }
  __syncthreads();
  if (t < 64){
    float q = pr[t]*pr[t] + pr[t+64]*pr[t+64];
    q += __shfl_xor(q, 1);  q += __shfl_xor(q, 2);  q += __shfl_xor(q, 4);
    q += __shfl_xor(q, 8);  q += __shfl_xor(q, 16); q += __shfl_xor(q, 32);
    if (t == 0) rns = 1.f / fmaxf(sqrtf(q), 1e-8f);
  }
  // tmat partial: part p sums c in [p*32, p*32+32)  (pr ready after first sync)
  {
    float a = 0.f;
    const int c0 = part * 32;
    #pragma unroll 8
    for (int c = c0; c < c0 + 32; ++c) a = fmaf(pr[c], W1[(size_t)(C_ + c)*C_ + h], a);
    sacc[part][h] = a;
  }
  __syncthreads();   // rns + sacc ready
  if (t < 128){
    // pn-pack: thread h handles k=h for class n
    short* packo = (short*)(ws + WS_PACK);
    const int gg = ((h >> 5)*64 + ((h >> 3) & 3)*16 + n)*8 + (h & 7);
    packo[32768 + gg] = f2bf(pr[h] * rns);
    ws[WS_T + n*C_ + h] = b1[h] + ((sacc[0][h] + sacc[1][h]) + (sacc[2][h] + sacc[3][h]));
  }
}

// ---- fused main: EXACT R15 (75.1 us) structure; cos store linearized ----
__global__ __launch_bounds__(256, 3) void fused_main(const float* __restrict__ qfeat,
                                                     const float* __restrict__ W1,
                                                     const float* __restrict__ b2,
                                                     const float* __restrict__ ws,
                                                     float* __restrict__ out){
  __shared__ __align__(16) char un[16896];   // qfs[32][132] f32 | hfrag[4q*2048] bf16
  __shared__ float qw[QB2][132];
  __shared__ float tl16[NC_][132];
  __shared__ float cosl[QB2][NC_];
  __shared__ float rqn[QB2];
  __shared__ float wcl[C_];

  float (*qfs)[132] = (float(*)[132])un;
  short* hfrag = (short*)un;

  const int t    = threadIdx.x;
  const int lane = t & 63;
  const int wv   = t >> 6;          // 0..3
  const int fr   = lane & 15;
  const int fg   = lane >> 4;
  const int qbase = blockIdx.x * QB2;
  float* out_cos = out + (size_t)NQ_ * NC_ * C_;
  const short* pack = (const short*)(ws + WS_PACK);

  // stage qf (32x128, row-clamped for tail block), t-matrix, Wc — all coalesced
  {
    const int q = t >> 3, c = (t & 7) * 16;
    int gr = qbase + q; if (gr > NQ_ - 1) gr = NQ_ - 1;
    const float* src = qfeat + (size_t)gr*C_ + c;
    *(f32x4*)&qfs[q][c]    = *(const f32x4*)(src);
    *(f32x4*)&qfs[q][c+4]  = *(const f32x4*)(src + 4);
    *(f32x4*)&qfs[q][c+8]  = *(const f32x4*)(src + 8);
    *(f32x4*)&qfs[q][c+12] = *(const f32x4*)(src + 12);
    const int r2 = t >> 4, c2 = (t & 15) * 8;
    *(f32x4*)&tl16[r2][c2]   = *(const f32x4*)(ws + WS_T + r2*C_ + c2);
    *(f32x4*)&tl16[r2][c2+4] = *(const f32x4*)(ws + WS_T + r2*C_ + c2 + 4);
    if (t < 32) *(f32x4*)&wcl[t*4] = *(const f32x4*)(W1 + 2*C_*C_ + t*4);
  }
  __syncthreads();

  // 1/max(||q||, eps) — 32 queries x 8 threads = 256 threads
  {
    const int q = t >> 3, c0 = (t & 7) * 16;
    float s = 0.f;
    #pragma unroll
    for (int m = 0; m < 16; ++m){ float v = qfs[q][c0+m]; s = fmaf(v, v, s); }
    s += __shfl_xor(s, 1); s += __shfl_xor(s, 2); s += __shfl_xor(s, 4);
    if ((t & 7) == 0) rqn[q] = 1.f / fmaxf(sqrtf(s), 1e-8f);
  }

  // A-fragments: group 0 = query fr, group 1 = query fr+16
  s16x8 qfrA[4], qfrB[4];
  #pragma unroll
  for (int ks = 0; ks < 4; ++ks){
    const int c0 = ks*32 + fg*8;
    f32x4 a = *(const f32x4*)&qfs[fr][c0];
    f32x4 b = *(const f32x4*)&qfs[fr][c0+4];
    s16x8 v;
    v[0]=f2bf(a[0]); v[1]=f2bf(a[1]); v[2]=f2bf(a[2]); v[3]=f2bf(a[3]);
    v[4]=f2bf(b[0]); v[5]=f2bf(b[1]); v[6]=f2bf(b[2]); v[7]=f2bf(b[3]);
    qfrA[ks] = v;
    f32x4 a2 = *(const f32x4*)&qfs[fr+16][c0];
    f32x4 b2x = *(const f32x4*)&qfs[fr+16][c0+4];
    s16x8 w;
    w[0]=f2bf(a2[0]); w[1]=f2bf(a2[1]); w[2]=f2bf(a2[2]); w[3]=f2bf(a2[3]);
    w[4]=f2bf(b2x[0]); w[5]=f2bf(b2x[1]); w[6]=f2bf(b2x[2]); w[7]=f2bf(b2x[3]);
    qfrB[ks] = w;
  }
  // B-fragments of W2 for this wave's two col-tiles
  s16x8 w2f[2][4];
  float b2v[2];
  #pragma unroll
  for (int j = 0; j < 2; ++j){
    const int tt = wv*2 + j;
    #pragma unroll
    for (int ks = 0; ks < 4; ++ks)
      w2f[j][ks] = *(const s16x8*)&pack[((tt*4 + ks)*64 + lane)*8];
    b2v[j] = b2[tt*16 + fr];
  }
  __syncthreads();   // rqn ready; all qfs reads done

  // qW = qf @ Wq for BOTH query groups : wave wv covers col-tiles wv*2, wv*2+1
  #pragma unroll
  for (int g = 0; g < 2; ++g){
    #pragma unroll
    for (int j = 0; j < 2; ++j){
      const int tt = wv*2 + j;
      f32x4 dq = {0.f,0.f,0.f,0.f};
      #pragma unroll
      for (int ks = 0; ks < 4; ++ks)
        dq = __builtin_amdgcn_mfma_f32_16x16x32_bf16(g ? qfrB[ks] : qfrA[ks],
               *(const s16x8*)&pack[16384 + ((tt*4 + ks)*64 + lane)*8], dq, 0,0,0);
      #pragma unroll
      for (int r = 0; r < 4; ++r) qw[g*16 + fg*4 + r][tt*16 + fr] = dq[r];
    }
  }
  // cos: wave 0 -> group 0 (q 0..15), wave 1 -> group 1 (q 16..31); store deferred
  if (wv < 2){
    f32x4 dc = {0.f,0.f,0.f,0.f};
    #pragma unroll
    for (int ks = 0; ks < 4; ++ks)
      dc = __builtin_amdgcn_mfma_f32_16x16x32_bf16(wv ? qfrB[ks] : qfrA[ks],
             *(const s16x8*)&pack[32768 + (ks*64 + lane)*8], dc, 0,0,0);
    #pragma unroll
    for (int r = 0; r < 4; ++r){
      const int q = wv*16 + fg*4 + r;
      cosl[q][fr] = dc[r] * rqn[q];
    }
  }
  __syncthreads();   // qw, cosl ready; qfs dead -> hfrag live

  // linear cos store: 2 KB contiguous per block (replaces scattered dwords)
  {
    const int q1 = t >> 4, q2 = 16 + (t >> 4), frc = t & 15;
    if (qbase + q1 < NQ_) out_cos[(size_t)qbase*NC_ + t]       = cosl[q1][frc];
    if (qbase + q2 < NQ_) out_cos[(size_t)qbase*NC_ + 256 + t] = cosl[q2][frc];
  }

  // phase-A constants: wave wv == k-step; lane -> (class fr, k-group fg)
  const int k0 = wv*32 + fg*8;
  const f32x4 t8a = *(const f32x4*)&tl16[fr][k0];
  const f32x4 t8b = *(const f32x4*)&tl16[fr][k0+4];
  const f32x4 w8a = *(const f32x4*)&wcl[k0];
  const f32x4 w8b = *(const f32x4*)&wcl[k0+4];

  #pragma unroll
  for (int chunk = 0; chunk < 8; ++chunk){
    const int q0 = chunk * 4;
    if (qbase + q0 >= NQ_) break;    // block-uniform tail cut (no barrier divergence)
    // phase A: H = relu(qW + t_n + cos*Wc) -> bf16 fragments
    #pragma unroll
    for (int qq = 0; qq < 4; ++qq){
      const int q = q0 + qq;
      f32x4 qa = *(const f32x4*)&qw[q][k0];     // broadcast within fg-group
      f32x4 qb = *(const f32x4*)&qw[q][k0+4];
      const float cv = cosl[q][fr];
      s16x8 hv;
      #pragma unroll
      for (int jj = 0; jj < 4; ++jj)
        hv[jj] = f2bf(fmaxf(fmaf(cv, w8a[jj], qa[jj] + t8a[jj]), 0.f));
      #pragma unroll
      for (int jj = 0; jj < 4; ++jj)
        hv[4+jj] = f2bf(fmaxf(fmaf(cv, w8b[jj], qb[jj] + t8b[jj]), 0.f));
      *(s16x8*)&hfrag[qq*2048 + wv*512 + lane*8] = hv;   // b128, conflict-free
    }
    __syncthreads();
    // phase B: sim = H @ W2 + b2 ; one ds_read set feeds both col-tiles
    #pragma unroll
    for (int qq = 0; qq < 4; ++qq){
      const short* hb = &hfrag[qq*2048 + lane*8];
      s16x8 a0 = *(const s16x8*)&hb[0];
      s16x8 a1 = *(const s16x8*)&hb[512];
      s16x8 a2 = *(const s16x8*)&hb[1024];
      s16x8 a3 = *(const s16x8*)&hb[1536];
      const size_t qout = (size_t)(qbase + q0 + qq) * (NC_*C_);
      #pragma unroll
      for (int j = 0; j < 2; ++j){
        f32x4 acc = {b2v[j], b2v[j], b2v[j], b2v[j]};
        acc = __builtin_amdgcn_mfma_f32_16x16x32_bf16(a0, w2f[j][0], acc, 0,0,0);
        acc = __builtin_amdgcn_mfma_f32_16x16x32_bf16(a1, w2f[j][1], acc, 0,0,0);
        acc = __builtin_amdgcn_mfma_f32_16x16x32_bf16(a2, w2f[j][2], acc, 0,0,0);
        acc = __builtin_amdgcn_mfma_f32_16x16x32_bf16(a3, w2f[j][3], acc, 0,0,0);
        const int ocol = (wv*2 + j)*16 + fr;
        #pragma unroll
        for (int r = 0; r < 4; ++r)
          out[qout + (fg*4 + r)*C_ + ocol] = acc[r];
      }
    }
    __syncthreads();
  }
}

extern "C" void kernel_launch(void* const* d_in, const int* in_sizes, int n_in,
                              void* d_out, int out_size, void* d_ws, size_t ws_size,
                              hipStream_t stream){
  const float* sf  = (const float*)d_in[0];
  const int*   lbl = (const int*)  d_in[1];
  const float* qf  = (const float*)d_in[2];
  const float* W1  = (const float*)d_in[3];
  const float* b1  = (const float*)d_in[4];
  const float* W2  = (const float*)d_in[5];
  const float* b2  = (const float*)d_in[6];
  float* ws  = (float*)d_ws;
  float* out = (float*)d_out;

  protoA<<<272, 256, 0, stream>>>(sf, lbl, W1, W2, ws);
  protoB<<<NC_, 512, 0, stream>>>(W1, b1, ws);
  fused_main<<<NBLK2, 256, 0, stream>>>(qf, W1, b2, ws, out);
}